// Round 6
// baseline (157.557 us; speedup 1.0000x reference)
//
#include <hip/hip_runtime.h>
#include <hip/hip_bf16.h>

#define Bv 32
#define Dv 512
#define Kv 64
#define Nv 1024
#define EPSv 1e-12f

typedef __attribute__((ext_vector_type(8))) short bf16x8;
typedef __attribute__((ext_vector_type(4))) float f32x4;

// fp32 -> bf16 (RNE), bit-level
__device__ __forceinline__ unsigned short f2b(float f) {
  union { float f; unsigned u; } v; v.f = f;
  unsigned r = v.u + 0x7fffu + ((v.u >> 16) & 1u);
  return (unsigned short)(r >> 16);
}
__device__ __forceinline__ unsigned pack2(float a, float b) {
  return (unsigned)f2b(a) | ((unsigned)f2b(b) << 16);
}

// ---------------------------------------------------------------------------
// Kernel W: convert conv_w (K x D fp32) -> bf16. 32 blocks x 256 thr.
// ---------------------------------------------------------------------------
__global__ __launch_bounds__(256) void wconv(const float* __restrict__ w,
                                             unsigned short* __restrict__ wbf) {
  int i = (blockIdx.x * 256 + threadIdx.x) * 4;
  float4 v = *(const float4*)&w[i];
  uint2 o = make_uint2(pack2(v.x, v.y), pack2(v.z, v.w));
  *(uint2*)&wbf[i] = o;
}

// ---------------------------------------------------------------------------
// Kernel 1 (fused): per (b, 64-n tile), in two 256-d halves:
//  - stage x fp32 [256d x 64n] -> LDS xT[n][d] bf16 (pitch 264)
//  - scores GEMM 64k x 64n via MFMA (A from wbf L2, B ds_read_b128)
// then softmax over k via shuffle + small LDS reductions, write assign bf16
// + asum atomics. NO xbf materialization (vlad re-reads x from LLC).
// Grid (N/64, B) = (16, 32) = 512 blocks, 512 threads (8 waves).
// LDS ~35.8 KB -> 4 blocks/CU, 32 waves/CU.
// ---------------------------------------------------------------------------
__global__ __launch_bounds__(512) void fused_scores(
    const float* __restrict__ x, const unsigned short* __restrict__ wbf,
    unsigned short* __restrict__ assign, float* __restrict__ asum) {
  __shared__ unsigned short xT[64 * 264];   // [n][d-half], pitch 264 shorts (528B)
  __shared__ float redmax[4][64];
  __shared__ float redsum[4][64];

  const int t = threadIdx.x;   // 0..511
  const int b = blockIdx.y;
  const int n0 = blockIdx.x * 64;
  const int wv = t >> 6;
  const int lane = t & 63;
  const int q = lane >> 4;
  const int m = lane & 15;
  const int k16 = wv & 3;       // k-tile
  const int nsub = wv >> 2;     // n-half: cols [nsub*32, +32)
  const int lo = t & 15;        // staging: n-quad
  const int hi = t >> 4;        // staging: 0..31

  f32x4 acc0 = {0.f, 0.f, 0.f, 0.f};
  f32x4 acc1 = {0.f, 0.f, 0.f, 0.f};

  const unsigned short* wp = wbf + (size_t)(k16 * 16 + m) * Dv + q * 8;
  const unsigned short* l0 = &xT[(nsub * 32 + m) * 264 + q * 8];
  const unsigned short* l1 = l0 + 16 * 264;

  for (int dh = 0; dh < 2; dh++) {
    // ---- stage 256 rows x 64 cols, transposed, paired rows per dword ----
    const float* xb = x + ((size_t)b * Dv + dh * 256) * Nv + n0;
#pragma unroll
    for (int r = 0; r < 4; r++) {
      int d = (hi + 32 * r) * 2;        // even row in half: 0..254
      int n4 = lo * 4;
      float4 v0 = *(const float4*)&xb[(size_t)d * Nv + n4];
      float4 v1 = *(const float4*)&xb[(size_t)(d + 1) * Nv + n4];
      *(unsigned*)&xT[(n4 + 0) * 264 + d] = pack2(v0.x, v1.x);
      *(unsigned*)&xT[(n4 + 1) * 264 + d] = pack2(v0.y, v1.y);
      *(unsigned*)&xT[(n4 + 2) * 264 + d] = pack2(v0.z, v1.z);
      *(unsigned*)&xT[(n4 + 3) * 264 + d] = pack2(v0.w, v1.w);
    }
    __syncthreads();
    // ---- GEMM over this d-half ----
#pragma unroll
    for (int d0 = 0; d0 < 256; d0 += 32) {
      bf16x8 af = *(const bf16x8*)(wp + dh * 256 + d0);
      bf16x8 bf0 = *(const bf16x8*)(l0 + d0);
      bf16x8 bf1 = *(const bf16x8*)(l1 + d0);
      acc0 = __builtin_amdgcn_mfma_f32_16x16x32_bf16(af, bf0, acc0, 0, 0, 0);
      acc1 = __builtin_amdgcn_mfma_f32_16x16x32_bf16(af, bf1, acc1, 0, 0, 0);
    }
    __syncthreads();
  }

  // ---------------- softmax over k (64) ----------------
  // lane (q,m) holds rows k16*16 + q*4 + r, cols n0 + nsub*32 + {m, 16+m}
  float m0 = fmaxf(fmaxf(acc0[0], acc0[1]), fmaxf(acc0[2], acc0[3]));
  float m1 = fmaxf(fmaxf(acc1[0], acc1[1]), fmaxf(acc1[2], acc1[3]));
  m0 = fmaxf(m0, __shfl_xor(m0, 16)); m0 = fmaxf(m0, __shfl_xor(m0, 32));
  m1 = fmaxf(m1, __shfl_xor(m1, 16)); m1 = fmaxf(m1, __shfl_xor(m1, 32));
  if (q == 0) {
    redmax[k16][nsub * 32 + m] = m0;
    redmax[k16][nsub * 32 + 16 + m] = m1;
  }
  __syncthreads();
  const int c0 = nsub * 32 + m, c1 = c0 + 16;
  float mc0 = fmaxf(fmaxf(redmax[0][c0], redmax[1][c0]), fmaxf(redmax[2][c0], redmax[3][c0]));
  float mc1 = fmaxf(fmaxf(redmax[0][c1], redmax[1][c1]), fmaxf(redmax[2][c1], redmax[3][c1]));

  float e0[4], e1[4];
  float s0 = 0.f, s1 = 0.f;
#pragma unroll
  for (int r = 0; r < 4; r++) {
    e0[r] = __expf(acc0[r] - mc0); s0 += e0[r];
    e1[r] = __expf(acc1[r] - mc1); s1 += e1[r];
  }
  s0 += __shfl_xor(s0, 16); s0 += __shfl_xor(s0, 32);
  s1 += __shfl_xor(s1, 16); s1 += __shfl_xor(s1, 32);
  if (q == 0) {
    redsum[k16][c0] = s0;
    redsum[k16][c1] = s1;
  }
  __syncthreads();
  float sc0 = 1.0f / (redsum[0][c0] + redsum[1][c0] + redsum[2][c0] + redsum[3][c0]);
  float sc1 = 1.0f / (redsum[0][c1] + redsum[1][c1] + redsum[2][c1] + redsum[3][c1]);

  // ---------------- assign write + asum ----------------
  unsigned short* ab = assign + ((size_t)b * Kv + k16 * 16 + q * 4) * Nv + n0 + nsub * 32;
#pragma unroll
  for (int r = 0; r < 4; r++) {
    float v0 = e0[r] * sc0;
    float v1 = e1[r] * sc1;
    ab[(size_t)r * Nv + m] = f2b(v0);
    ab[(size_t)r * Nv + 16 + m] = f2b(v1);
    float p = v0 + v1;
    p += __shfl_xor(p, 1); p += __shfl_xor(p, 2);
    p += __shfl_xor(p, 4); p += __shfl_xor(p, 8);
    if (m == 0) atomicAdd(&asum[b * Kv + k16 * 16 + q * 4 + r], p);
  }
}

// ---------------------------------------------------------------------------
// Kernel 2: vlad[b,d,k] = sum_n x*assign - centers*asum via bf16 MFMA.
// x read directly as fp32 (LLC-warm from kernel 1) with inline bf16 cvt.
// n-contraction split across wave pairs (LDS reduce) -> 2048 blocks,
// 8 blocks/CU x 4 waves = 32 waves/CU. Fuses colsq.
// Grid ((D/16)*(K/32), B) = (64, 32), 256 threads.
// ---------------------------------------------------------------------------
__global__ __launch_bounds__(256) void vlad_mfma(
    const float* __restrict__ x, const unsigned short* __restrict__ assign,
    const float* __restrict__ centers, const float* __restrict__ asum,
    float* __restrict__ vlad, float* __restrict__ colsq) {
  __shared__ float sred[2][64][4];   // [ksub][lane][r] from nh==1 waves

  const int t = threadIdx.x;
  const int b = blockIdx.y;
  const int gx = blockIdx.x;         // 0..63
  const int d0 = (gx >> 1) * 16;
  const int kb = (gx & 1) * 32;
  const int wv = t >> 6;
  const int ksub = wv & 1;
  const int nh = wv >> 1;            // n-half
  const int lane = t & 63;
  const int q = lane >> 4;
  const int m = lane & 15;
  const int k16 = kb + ksub * 16;

  f32x4 acc0 = {0.f, 0.f, 0.f, 0.f};
  f32x4 acc1 = {0.f, 0.f, 0.f, 0.f};

  const float* xp = x + ((size_t)b * Dv + d0 + m) * Nv + nh * 512 + q * 8;
  const unsigned short* ap = assign + ((size_t)b * Kv + k16 + m) * Nv + nh * 512 + q * 8;

#pragma unroll 4
  for (int n = 0; n < 512; n += 64) {
    float4 xa0 = *(const float4*)(xp + n);
    float4 xc0 = *(const float4*)(xp + n + 4);
    bf16x8 f0 = *(const bf16x8*)(ap + n);
    float4 xa1 = *(const float4*)(xp + n + 32);
    float4 xc1 = *(const float4*)(xp + n + 36);
    bf16x8 f1 = *(const bf16x8*)(ap + n + 32);
    bf16x8 a0, a1;
    a0[0] = (short)f2b(xa0.x); a0[1] = (short)f2b(xa0.y);
    a0[2] = (short)f2b(xa0.z); a0[3] = (short)f2b(xa0.w);
    a0[4] = (short)f2b(xc0.x); a0[5] = (short)f2b(xc0.y);
    a0[6] = (short)f2b(xc0.z); a0[7] = (short)f2b(xc0.w);
    a1[0] = (short)f2b(xa1.x); a1[1] = (short)f2b(xa1.y);
    a1[2] = (short)f2b(xa1.z); a1[3] = (short)f2b(xa1.w);
    a1[4] = (short)f2b(xc1.x); a1[5] = (short)f2b(xc1.y);
    a1[6] = (short)f2b(xc1.z); a1[7] = (short)f2b(xc1.w);
    acc0 = __builtin_amdgcn_mfma_f32_16x16x32_bf16(a0, f0, acc0, 0, 0, 0);
    acc1 = __builtin_amdgcn_mfma_f32_16x16x32_bf16(a1, f1, acc1, 0, 0, 0);
  }

  f32x4 v;
#pragma unroll
  for (int r = 0; r < 4; r++) v[r] = acc0[r] + acc1[r];

  if (nh == 1) {
#pragma unroll
    for (int r = 0; r < 4; r++) sred[ksub][lane][r] = v[r];
  }
  __syncthreads();
  if (nh == 0) {
    const int k = k16 + m;
    const float as = asum[b * Kv + k];
    float ss = 0.f;
#pragma unroll
    for (int r = 0; r < 4; r++) {
      v[r] += sred[ksub][lane][r];
      int d = d0 + q * 4 + r;
      float val = v[r] - centers[d * Kv + k] * as;
      vlad[((size_t)b * Dv + d) * Kv + k] = val;
      ss = fmaf(val, val, ss);
    }
    ss += __shfl_xor(ss, 16);
    ss += __shfl_xor(ss, 32);
    if (q == 0) atomicAdd(&colsq[b * Kv + k], ss);
  }
}

// ---------------------------------------------------------------------------
// Kernel D: out = vlad * colscale[b,k] * bscale[b]; scales from colsq
// in-block. Grid 4096 x 256.
// ---------------------------------------------------------------------------
__global__ __launch_bounds__(256) void scale_kernel(
    const float* __restrict__ vlad, const float* __restrict__ colsq,
    float* __restrict__ out) {
  const int t = threadIdx.x;
  const size_t i = (size_t)blockIdx.x * 256 + t;
  const int b = (int)(i >> 15);  // D*K = 32768 per b
  __shared__ float scs[64];
  __shared__ float bsh;
  if (t < 64) {
    float tot = colsq[b * Kv + t];
    float sc = 1.0f / fmaxf(sqrtf(tot), EPSv);
    scs[t] = sc;
    float contrib = tot * sc * sc;
#pragma unroll
    for (int off = 32; off > 0; off >>= 1) contrib += __shfl_down(contrib, off);
    if (t == 0) bsh = 1.0f / fmaxf(sqrtf(contrib), EPSv);
  }
  __syncthreads();
  out[i] = vlad[i] * scs[i & 63] * bsh;
}

extern "C" void kernel_launch(void* const* d_in, const int* in_sizes, int n_in,
                              void* d_out, int out_size, void* d_ws, size_t ws_size,
                              hipStream_t stream) {
  const float* x = (const float*)d_in[0];        // [B, D, N]
  const float* w = (const float*)d_in[1];        // [K, D]
  const float* centers = (const float*)d_in[2];  // [D, K]
  float* out = (float*)d_out;                    // [B, D*K]

  char* ws = (char*)d_ws;
  unsigned short* assign = (unsigned short*)ws;               // [B][K][N] bf16, 4 MB
  float* vlad = (float*)(ws + 4194304);                       // [B][D][K] fp32, 4 MB
  unsigned short* wbf = (unsigned short*)(ws + 8388608);      // [K][D] bf16, 64 KB
  float* asum = (float*)(ws + 8454144);                       // B*K
  float* colsq = asum + Bv * Kv;                              // B*K

  hipMemsetAsync(asum, 0, (size_t)2 * Bv * Kv * sizeof(float), stream);

  wconv<<<32, 256, 0, stream>>>(w, wbf);
  fused_scores<<<dim3(Nv / 64, Bv), 512, 0, stream>>>(x, wbf, assign, asum);
  vlad_mfma<<<dim3(64, Bv), 256, 0, stream>>>(x, assign, centers, asum, vlad, colsq);
  scale_kernel<<<(Bv * Dv * Kv) / 256, 256, 0, stream>>>(vlad, colsq, out);
}

// Round 7
// 156.576 us; speedup vs baseline: 1.0063x; 1.0063x over previous
//
#include <hip/hip_runtime.h>
#include <hip/hip_bf16.h>

#define Bv 32
#define Dv 512
#define Kv 64
#define Nv 1024
#define EPSv 1e-12f

typedef __attribute__((ext_vector_type(8))) short bf16x8;
typedef __attribute__((ext_vector_type(4))) float f32x4;

// fp32 -> bf16 (RNE), bit-level
__device__ __forceinline__ unsigned short f2b(float f) {
  union { float f; unsigned u; } v; v.f = f;
  unsigned r = v.u + 0x7fffu + ((v.u >> 16) & 1u);
  return (unsigned short)(r >> 16);
}
__device__ __forceinline__ unsigned pack2(float a, float b) {
  return (unsigned)f2b(a) | ((unsigned)f2b(b) << 16);
}
__device__ __forceinline__ float b2f(unsigned short s) {
  union { unsigned u; float f; } v; v.u = (unsigned)s << 16; return v.f;
}

// ---------------------------------------------------------------------------
// Kernel W: convert conv_w (K x D fp32) -> bf16. 32 blocks x 256 thr.
// ---------------------------------------------------------------------------
__global__ __launch_bounds__(256) void wconv(const float* __restrict__ w,
                                             unsigned short* __restrict__ wbf) {
  int i = (blockIdx.x * 256 + threadIdx.x) * 4;
  float4 v = *(const float4*)&w[i];
  uint2 o = make_uint2(pack2(v.x, v.y), pack2(v.z, v.w));
  *(uint2*)&wbf[i] = o;
}

// ---------------------------------------------------------------------------
// Kernel 1 (fused): per (b, 32-n tile):
//  - stage x fp32 [512d x 32n] -> LDS xT[n][d] bf16 (pitch 520) + xbf global
//  - scores GEMM 64k x 32n via MFMA (A from wbf L2, B ds_read_b128, 16 iters)
//  - softmax over k via shuffle + small LDS cross-wave reductions
//  - write assign bf16. No asum here (vlad recomputes it from assign).
// Grid (N/32, B) = (32, 32) = 1024 blocks, 512 threads (8 waves).
// LDS ~34 KB -> 4 blocks/CU, 32 waves/CU.
// ---------------------------------------------------------------------------
__global__ __launch_bounds__(512) void fused_scores(
    const float* __restrict__ x, const unsigned short* __restrict__ wbf,
    unsigned short* __restrict__ xbf, unsigned short* __restrict__ assign) {
  __shared__ unsigned short xT[32 * 520];   // [n][d], pitch 520 shorts (1040B)
  __shared__ float redmax[4][32];
  __shared__ float redsum[4][32];

  const int t = threadIdx.x;   // 0..511
  const int b = blockIdx.y;
  const int n0 = blockIdx.x * 32;

  // ---------------- staging (also writes xbf) ----------------
  {
    const int lo = t & 7;      // n-quad: n4 = lo*4
    const int hi = t >> 3;     // 0..63 (d-pair subindex)
    const float* xb = x + (size_t)b * Dv * Nv + n0;
    unsigned short* xo = xbf + (size_t)b * Dv * Nv + n0;
#pragma unroll
    for (int r = 0; r < 4; r++) {
      int d = (hi + 64 * r) * 2;        // even d: 0..510
      int n4 = lo * 4;
      float4 v0 = *(const float4*)&xb[(size_t)d * Nv + n4];
      float4 v1 = *(const float4*)&xb[(size_t)(d + 1) * Nv + n4];
      *(uint2*)&xo[(size_t)d * Nv + n4] =
          make_uint2(pack2(v0.x, v0.y), pack2(v0.z, v0.w));
      *(uint2*)&xo[(size_t)(d + 1) * Nv + n4] =
          make_uint2(pack2(v1.x, v1.y), pack2(v1.z, v1.w));
      // LDS xT: dword at [n][d] = (x[d][n], x[d+1][n]); d even -> aligned
      *(unsigned*)&xT[(n4 + 0) * 520 + d] = pack2(v0.x, v1.x);
      *(unsigned*)&xT[(n4 + 1) * 520 + d] = pack2(v0.y, v1.y);
      *(unsigned*)&xT[(n4 + 2) * 520 + d] = pack2(v0.z, v1.z);
      *(unsigned*)&xT[(n4 + 3) * 520 + d] = pack2(v0.w, v1.w);
    }
  }
  __syncthreads();

  // ---------------- scores GEMM ----------------
  const int wv = t >> 6;        // 0..7
  const int lane = t & 63;
  const int q = lane >> 4;
  const int m = lane & 15;
  const int k16 = wv & 3;       // k-tile
  const int nsub = wv >> 2;     // n-half: cols [nsub*16, +16)

  f32x4 acc = {0.f, 0.f, 0.f, 0.f};
  const unsigned short* wp = wbf + (size_t)(k16 * 16 + m) * Dv + q * 8;
  const unsigned short* lp = &xT[(nsub * 16 + m) * 520 + q * 8];

#pragma unroll
  for (int d0 = 0; d0 < Dv; d0 += 32) {
    bf16x8 af = *(const bf16x8*)(wp + d0);
    bf16x8 bf = *(const bf16x8*)(lp + d0);
    acc = __builtin_amdgcn_mfma_f32_16x16x32_bf16(af, bf, acc, 0, 0, 0);
  }

  // ---------------- softmax over k (64) ----------------
  // lane (q,m): rows k16*16 + q*4 + r, col n0 + nsub*16 + m
  float mx = fmaxf(fmaxf(acc[0], acc[1]), fmaxf(acc[2], acc[3]));
  mx = fmaxf(mx, __shfl_xor(mx, 16));
  mx = fmaxf(mx, __shfl_xor(mx, 32));
  if (q == 0) redmax[k16][nsub * 16 + m] = mx;
  __syncthreads();
  const int c = nsub * 16 + m;
  float mc = fmaxf(fmaxf(redmax[0][c], redmax[1][c]),
                   fmaxf(redmax[2][c], redmax[3][c]));
  float e[4];
  float s = 0.f;
#pragma unroll
  for (int r = 0; r < 4; r++) { e[r] = __expf(acc[r] - mc); s += e[r]; }
  s += __shfl_xor(s, 16);
  s += __shfl_xor(s, 32);
  if (q == 0) redsum[k16][c] = s;
  __syncthreads();
  float sc = 1.0f / (redsum[0][c] + redsum[1][c] + redsum[2][c] + redsum[3][c]);

  // ---------------- assign write ----------------
  unsigned short* ab = assign + ((size_t)b * Kv + k16 * 16 + q * 4) * Nv + n0 + nsub * 16;
#pragma unroll
  for (int r = 0; r < 4; r++) ab[(size_t)r * Nv + m] = f2b(e[r] * sc);
}

// ---------------------------------------------------------------------------
// Kernel 2: vlad[b,d,k] = sum_n xbf*assign - centers*asum via bf16 MFMA.
// One block owns ALL 64 k for a 16-d stripe -> x-tile read exactly once
// (no cross-block x redundancy). asum computed in-kernel from the same
// assign bf16 values (shuffle + LDS reduce) -- no global asum at all.
// Grid (D/16, B) = (32, 32) = 1024 blocks, 512 threads (8 waves):
// wave = (ksub 0..3, nh 0..1). Fuses colsq via atomics.
// ---------------------------------------------------------------------------
__global__ __launch_bounds__(512) void vlad_mfma(
    const unsigned short* __restrict__ xbf, const unsigned short* __restrict__ assign,
    const float* __restrict__ centers, float* __restrict__ vlad,
    float* __restrict__ colsq) {
  __shared__ float sred[4][64][4];   // [ksub][lane][r] from nh==1 waves
  __shared__ float sasum[4][16];     // [ksub][m] half-asum from nh==1

  const int t = threadIdx.x;
  const int b = blockIdx.y;
  const int d0 = blockIdx.x * 16;
  const int wv = t >> 6;
  const int ksub = wv & 3;
  const int nh = wv >> 2;            // n-half
  const int lane = t & 63;
  const int q = lane >> 4;
  const int m = lane & 15;
  const int k16 = ksub * 16;

  f32x4 acc = {0.f, 0.f, 0.f, 0.f};
  float sa = 0.f;

  const unsigned short* xp = xbf + ((size_t)b * Dv + d0 + m) * Nv + nh * 512 + q * 8;
  const unsigned short* ap = assign + ((size_t)b * Kv + k16 + m) * Nv + nh * 512 + q * 8;

#pragma unroll
  for (int n = 0; n < 512; n += 32) {
    bf16x8 a0 = *(const bf16x8*)(xp + n);
    bf16x8 f0 = *(const bf16x8*)(ap + n);
    acc = __builtin_amdgcn_mfma_f32_16x16x32_bf16(a0, f0, acc, 0, 0, 0);
#pragma unroll
    for (int j = 0; j < 8; j++) sa += b2f((unsigned short)f0[j]);
  }

  // asum partial for row k16+m over this n-half: reduce over q
  sa += __shfl_xor(sa, 16);
  sa += __shfl_xor(sa, 32);

  if (nh == 1) {
#pragma unroll
    for (int r = 0; r < 4; r++) sred[ksub][lane][r] = acc[r];
    if (q == 0) sasum[ksub][m] = sa;
  }
  __syncthreads();
  if (nh == 0) {
    const int k = k16 + m;
    const float asum_k = sa + sasum[ksub][m];
    float ss = 0.f;
#pragma unroll
    for (int r = 0; r < 4; r++) {
      float v = acc[r] + sred[ksub][lane][r];
      int d = d0 + q * 4 + r;
      float val = v - centers[d * Kv + k] * asum_k;
      vlad[((size_t)b * Dv + d) * Kv + k] = val;
      ss = fmaf(val, val, ss);
    }
    ss += __shfl_xor(ss, 16);
    ss += __shfl_xor(ss, 32);
    if (q == 0) atomicAdd(&colsq[b * Kv + k], ss);
  }
}

// ---------------------------------------------------------------------------
// Kernel D: out = vlad * colscale[b,k] * bscale[b]; scales from colsq
// in-block. Grid 4096 x 256.
// ---------------------------------------------------------------------------
__global__ __launch_bounds__(256) void scale_kernel(
    const float* __restrict__ vlad, const float* __restrict__ colsq,
    float* __restrict__ out) {
  const int t = threadIdx.x;
  const size_t i = (size_t)blockIdx.x * 256 + t;
  const int b = (int)(i >> 15);  // D*K = 32768 per b
  __shared__ float scs[64];
  __shared__ float bsh;
  if (t < 64) {
    float tot = colsq[b * Kv + t];
    float sc = 1.0f / fmaxf(sqrtf(tot), EPSv);
    scs[t] = sc;
    float contrib = tot * sc * sc;
#pragma unroll
    for (int off = 32; off > 0; off >>= 1) contrib += __shfl_down(contrib, off);
    if (t == 0) bsh = 1.0f / fmaxf(sqrtf(contrib), EPSv);
  }
  __syncthreads();
  out[i] = vlad[i] * scs[i & 63] * bsh;
}

extern "C" void kernel_launch(void* const* d_in, const int* in_sizes, int n_in,
                              void* d_out, int out_size, void* d_ws, size_t ws_size,
                              hipStream_t stream) {
  const float* x = (const float*)d_in[0];        // [B, D, N]
  const float* w = (const float*)d_in[1];        // [K, D]
  const float* centers = (const float*)d_in[2];  // [D, K]
  float* out = (float*)d_out;                    // [B, D*K]

  char* ws = (char*)d_ws;
  unsigned short* assign = (unsigned short*)ws;               // [B][K][N] bf16, 4 MB
  float* vlad = (float*)(ws + 4194304);                       // [B][D][K] fp32, 4 MB
  unsigned short* xbf = (unsigned short*)(ws + 8388608);      // [B][D][N] bf16, 32 MB
  unsigned short* wbf = (unsigned short*)(ws + 41943040);     // [K][D] bf16, 64 KB
  float* colsq = (float*)(ws + 42008576);                     // B*K

  hipMemsetAsync(colsq, 0, (size_t)Bv * Kv * sizeof(float), stream);

  wconv<<<32, 256, 0, stream>>>(w, wbf);
  fused_scores<<<dim3(Nv / 32, Bv), 512, 0, stream>>>(x, wbf, xbf, assign);
  vlad_mfma<<<dim3(Dv / 16, Bv), 512, 0, stream>>>(xbf, assign, centers, vlad, colsq);
  scale_kernel<<<(Bv * Dv * Kv) / 256, 256, 0, stream>>>(vlad, colsq, out);
}